// Round 2
// baseline (22806.953 us; speedup 1.0000x reference)
//
#include <hip/hip_runtime.h>
#include <hip/hip_cooperative_groups.h>
#include <math.h>

namespace cg = cooperative_groups;

// Problem constants (from reference setup_inputs)
#define BB 64      // batch
#define TT 512     // time steps
#define DD 256     // input dim
#define HH 512     // hidden dim
#define GG 2048    // 4*H gate width
#define KX 768     // D+H concat K dim
#define CTXF 49152 // context_state floats (B * KX) — traj_h starts after this
#define KXP (KX + 4) // padded LDS row: 772 floats -> bank shift of 4 per row

// ---------------------------------------------------------------------------
// pack VU^T: vut[k][j] = j<D ? W[j][k] : U[j-D][k]   (k in [0,2048), j in [0,768))
// ---------------------------------------------------------------------------
__global__ void pack_vut(const float* __restrict__ Wm, const float* __restrict__ Um,
                         float* __restrict__ vut) {
    __shared__ float tile[32][33];
    int k0 = blockIdx.x * 32;
    int j0 = blockIdx.y * 32;
    int lx = threadIdx.x & 31;
    int ly = threadIdx.x >> 5;
    for (int r = ly; r < 32; r += 8) {
        int j = j0 + r, k = k0 + lx;
        tile[r][lx] = (j < DD) ? Wm[j * GG + k] : Um[(j - DD) * GG + k];
    }
    __syncthreads();
    for (int r = ly; r < 32; r += 8) {
        int k = k0 + r, j = j0 + lx;
        vut[(long)k * KX + j] = tile[lx][r];
    }
}

// ---------------------------------------------------------------------------
__global__ void init_state(float* __restrict__ h) {
    int idx = blockIdx.x * 256 + threadIdx.x;
    if (idx < 2 * BB * HH) h[idx] = 0.f;
}

// ---------------------------------------------------------------------------
// copy x into traj_h[:, :, 0:256] and context_state[:, 0:256]
// ---------------------------------------------------------------------------
__global__ void xcopy(const float* __restrict__ x, float* __restrict__ out) {
    const long n_traj = (long)BB * TT * (DD / 4);
    long idx = (long)blockIdx.x * 256 + threadIdx.x;
    const float4* x4 = (const float4*)x;
    float4* out4 = (float4*)out;
    if (idx < n_traj) {
        long bt = idx / (DD / 4);
        int d4 = (int)(idx % (DD / 4));
        out4[(CTXF / 4) + bt * (KX / 4) + d4] = x4[idx];
    } else if (idx < n_traj + BB * (DD / 4)) {
        long f = idx - n_traj;
        int b = (int)(f / (DD / 4)), d4 = (int)(f % (DD / 4));
        out4[(long)b * (KX / 4) + d4] = x4[((long)b * TT + (TT - 1)) * (DD / 4) + d4];
    }
}

// ---------------------------------------------------------------------------
// Persistent LSTM scan. 256 WGs x 512 threads, cooperative.
// WG(jb=wg&63, bg=wg>>6) owns j in [jb*8, jb*8+8) x batches [bg*16, bg*16+16).
// Thread tid: b = tid&15, cl = tid>>4 (0..31 = gate*8+jj). One z output each.
// c state lives in updater-thread registers (cl<8) for the whole scan.
// ---------------------------------------------------------------------------
__global__ __launch_bounds__(512) void lstm_persist(
    const float* __restrict__ vut, const float* __restrict__ bias,
    const float* __restrict__ x, float* __restrict__ h,
    float* __restrict__ out)
{
    cg::grid_group grid = cg::this_grid();
    __shared__ float xh[16][KXP];  // 49.4 KB: [x_t | h] for 16 batches
    __shared__ float zs[16][33];   // z exchange for gate combine

    const int wg = blockIdx.x;
    const int jb = wg & 63;
    const int bg = wg >> 6;
    const int b0 = bg * 16;
    const int j0 = jb * 8;
    const int tid = threadIdx.x;
    const int b   = tid & 15;
    const int cl  = tid >> 4;          // 0..31
    const int gate = cl >> 3;
    const int jj   = cl & 7;
    const int col  = gate * HH + j0 + jj;

    const float bcol = bias[col];
    const float4* vrow = (const float4*)(vut + (long)col * KX);
    const float4* x4g  = (const float4*)x;

    float creg = 0.f;                  // cell state (updater threads only)

    // x-prefetch: this thread stages float4 slots {tid, tid+512} of the 1024
    const int pb0 = tid >> 6;          // batch-local 0..7
    const int pd0 = tid & 63;          // d4 0..63
    const int pb1 = pb0 + 8;           // batch-local 8..15
    float4 xp0 = x4g[((long)((b0 + pb0) * TT + 0)) * (DD / 4) + pd0];
    float4 xp1 = x4g[((long)((b0 + pb1) * TT + 0)) * (DD / 4) + pd0];

    for (int t = 0; t < TT; ++t) {
        // ---- stage xh = [x_t | h_prev] ----
        ((float4*)&xh[pb0][0])[pd0] = xp0;
        ((float4*)&xh[pb1][0])[pd0] = xp1;
        const float* hp = h + (t & 1) * (BB * HH);
        #pragma unroll
        for (int s = 0; s < 4; ++s) {
            int i = tid + s * 512;
            int bb = i >> 7, j4 = i & 127;
            ((float4*)&xh[bb][DD])[j4] = ((const float4*)hp)[(b0 + bb) * (HH / 4) + j4];
        }
        __syncthreads();

        // prefetch next step's x while computing
        if (t + 1 < TT) {
            xp0 = x4g[((long)((b0 + pb0) * TT + (t + 1))) * (DD / 4) + pd0];
            xp1 = x4g[((long)((b0 + pb1) * TT + (t + 1))) * (DD / 4) + pd0];
        }

        // ---- dot product: z[col][b] over K=768 ----
        float ax = 0.f, ay = 0.f, az = 0.f, aw = 0.f;
        const float4* xp = (const float4*)&xh[b][0];
        #pragma unroll 4
        for (int i = 0; i < KX / 4; ++i) {
            float4 w = vrow[i];
            float4 v = xp[i];
            ax += w.x * v.x; ay += w.y * v.y; az += w.z * v.z; aw += w.w * v.w;
        }
        zs[b][cl] = (ax + ay) + (az + aw) + bcol;
        __syncthreads();

        // ---- gate combine + state update (cl<8: one (j,b) each) ----
        if (cl < 8) {
            float iv = tanhf(zs[b][jj]);
            float fv = tanhf(zs[b][8 + jj]);
            float gv = tanhf(zs[b][16 + jj]);
            float ov = tanhf(zs[b][24 + jj]);
            float c2 = fv * creg + iv * gv;
            float h2 = ov * tanhf(c2);
            creg = c2;
            const int gb = b0 + b, gj = j0 + jj;
            float* hn = h + ((t + 1) & 1) * (BB * HH);
            hn[gb * HH + gj] = h2;
            out[CTXF + ((long)(gb * TT + t)) * KX + DD + gj] = h2;
            if (t == TT - 1) out[(long)gb * KX + DD + gj] = h2;
        }
        grid.sync();
    }
}

// ---------------------------------------------------------------------------
extern "C" void kernel_launch(void* const* d_in, const int* in_sizes, int n_in,
                              void* d_out, int out_size, void* d_ws, size_t ws_size,
                              hipStream_t stream) {
    (void)in_sizes; (void)n_in; (void)out_size; (void)ws_size;
    const float* x    = (const float*)d_in[0];
    const float* Wm   = (const float*)d_in[1];
    const float* Um   = (const float*)d_in[2];
    const float* bias = (const float*)d_in[3];
    float* out = (float*)d_out;
    float* ws  = (float*)d_ws;

    float* vut = ws;                   // 2048*768 floats
    float* h   = ws + 1572864;         // 2 * 64*512 floats (double buffer)

    hipLaunchKernelGGL(pack_vut, dim3(64, 24), dim3(256), 0, stream, Wm, Um, vut);
    hipLaunchKernelGGL(init_state, dim3(256), dim3(256), 0, stream, h);
    hipLaunchKernelGGL(xcopy, dim3(8209), dim3(256), 0, stream, x, out);

    void* args[] = {(void*)&vut, (void*)&bias, (void*)&x, (void*)&h, (void*)&out};
    hipLaunchCooperativeKernel((const void*)lstm_persist, dim3(256), dim3(512),
                               args, 0, stream);
}

// Round 4
// 22801.906 us; speedup vs baseline: 1.0002x; 1.0002x over previous
//
#include <hip/hip_runtime.h>
#include <hip/hip_cooperative_groups.h>
#include <math.h>

namespace cg = cooperative_groups;

// Problem constants
#define BB 64      // batch
#define TT 512     // time steps
#define DD 256     // input dim
#define HH 512     // hidden dim
#define GG 2048    // 4*H
#define KX 768     // D+H concat K
#define K4 192     // KX/4 float4s per row
#define CTXF 49152 // context_state floats; traj_h starts after

// ---------------------------------------------------------------------------
// pack VU^T: vut[col][k] = k<D ? W[k][col] : U[k-D][col]
// ---------------------------------------------------------------------------
__global__ void pack_vut(const float* __restrict__ Wm, const float* __restrict__ Um,
                         float* __restrict__ vut) {
    __shared__ float tile[32][33];
    int k0 = blockIdx.x * 32;   // col block (2048)
    int j0 = blockIdx.y * 32;   // K block (768)
    int lx = threadIdx.x & 31;
    int ly = threadIdx.x >> 5;
    for (int r = ly; r < 32; r += 8) {
        int j = j0 + r, k = k0 + lx;
        tile[r][lx] = (j < DD) ? Wm[j * GG + k] : Um[(j - DD) * GG + k];
    }
    __syncthreads();
    for (int r = ly; r < 32; r += 8) {
        int k = k0 + r, j = j0 + lx;
        vut[(long)k * KX + j] = tile[lx][r];
    }
}

__global__ void init_state(float* __restrict__ h) {
    int idx = blockIdx.x * 256 + threadIdx.x;
    if (idx < 2 * BB * HH) h[idx] = 0.f;
}

// ---------------------------------------------------------------------------
// copy x into traj_h[:, :, 0:256] and context_state[:, 0:256]
// ---------------------------------------------------------------------------
__global__ void xcopy(const float* __restrict__ x, float* __restrict__ out) {
    const long n_traj = (long)BB * TT * (DD / 4);
    long idx = (long)blockIdx.x * 256 + threadIdx.x;
    const float4* x4 = (const float4*)x;
    float4* out4 = (float4*)out;
    if (idx < n_traj) {
        long bt = idx / (DD / 4);
        int d4 = (int)(idx % (DD / 4));
        out4[(CTXF / 4) + bt * (KX / 4) + d4] = x4[idx];
    } else if (idx < n_traj + BB * (DD / 4)) {
        long f = idx - n_traj;
        int b = (int)(f / (DD / 4)), d4 = (int)(f % (DD / 4));
        out4[(long)b * (KX / 4) + d4] = x4[((long)b * TT + (TT - 1)) * (DD / 4) + d4];
    }
}

// ---------------------------------------------------------------------------
// Persistent LSTM. 256 WGs x 512 threads, cooperative, 1 WG/CU.
// WG(jb=wg&63, bg=wg>>6): j in [jb*8, jb*8+8) x batches [bg*16, bg*16+16).
// 32 gate-cols (8 j x 4 gates) with weights LDS-resident (96 KB, XOR-swizzled).
// Thread: ks=tid>>5 (K-slice of 48), ct=(tid>>2)&7 (=jj, 4 gate-cols),
// bt=tid&3 (4 batches {bt,bt+4,bt+8,bt+12}). 4x4 float4 accum tile.
// K-partials reduced via LDS atomicAdd into zsum (bias-preinitialized).
// ---------------------------------------------------------------------------
#define FMA4(A, Wv, Hv) \
    A.x += Wv.x * Hv.x; A.y += Wv.y * Hv.y; A.z += Wv.z * Hv.z; A.w += Wv.w * Hv.w;

__global__ __launch_bounds__(512) void lstm_persist(
    const float* __restrict__ vut, const float* __restrict__ bias,
    const float* __restrict__ x, float* __restrict__ h,
    float* __restrict__ out)
{
    cg::grid_group grid = cg::this_grid();
    __shared__ float4 w_lds[32 * K4];   // 98304 B, row r: [r*K4 + (k4 ^ (r&7))]
    __shared__ float4 xh[16 * K4];      // 49152 B, row b: [b*K4 + (k4 ^ (b&7))]
    __shared__ float  zsum[2][512];     //  4096 B, [parity][r*16 + b]

    const int wg = blockIdx.x;
    const int jb = wg & 63;
    const int bg = wg >> 6;
    const int b0 = bg * 16;
    const int j0 = jb * 8;
    const int tid = threadIdx.x;
    const int ks = tid >> 5;          // 0..15 K-slice
    const int ct = (tid >> 2) & 7;    // = jj
    const int bt = tid & 3;

    const float4* x4g = (const float4*)x;

    // ---- stage weights into LDS once (swizzled) ----
    for (int i = tid; i < 32 * K4; i += 512) {
        int r = i / K4;
        int k4 = i - r * K4;
        int col = (r >> 3) * HH + j0 + (r & 7);
        w_lds[r * K4 + (k4 ^ (r & 7))] =
            ((const float4*)(vut + (long)col * KX))[k4];
    }
    // ---- per-thread bias for zsum entry tid (r=tid>>4, b=tid&15) ----
    const int zr = tid >> 4;
    const float biasreg = bias[(zr >> 3) * HH + j0 + (zr & 7)];
    zsum[0][tid] = biasreg;

    float creg = 0.f;   // cell state for combiner threads (tid<128)

    // ---- x prefetch regs: items {tid, tid+512} of 1024 float4 ----
    const int xb1 = tid >> 6, xk1 = tid & 63;
    const int xb2 = 8 + xb1;
    float4 xp1 = x4g[((long)(b0 + xb1) * TT + 0) * 64 + xk1];
    float4 xp2 = x4g[((long)(b0 + xb2) * TT + 0) * 64 + xk1];

    // LDS base pointers for GEMM
    const float4* wl0 = &w_lds[(ct) * K4];
    const float4* wl1 = &w_lds[(8 + ct) * K4];
    const float4* wl2 = &w_lds[(16 + ct) * K4];
    const float4* wl3 = &w_lds[(24 + ct) * K4];
    const float4* xr0 = &xh[(bt) * K4];
    const float4* xr1 = &xh[(bt + 4) * K4];
    const float4* xr2 = &xh[(bt + 8) * K4];
    const float4* xr3 = &xh[(bt + 12) * K4];

    for (int t = 0; t < TT; ++t) {
        const int p = t & 1;
        const float* hp = h + p * (BB * HH);
        float* hn = h + (1 - p) * (BB * HH);

        // ---- (a) stage xh: x-part from prefetch regs, h-part from global ----
        xh[xb1 * K4 + (xk1 ^ (xb1 & 7))] = xp1;
        xh[xb2 * K4 + (xk1 ^ (xb2 & 7))] = xp2;
        #pragma unroll
        for (int s = 0; s < 4; ++s) {
            int i = tid + s * 512;          // 0..2047
            int b = i >> 7, k4h = i & 127;
            // BUGFIX (R3->R4): h row must include the batch-group offset b0.
            float4 v = ((const float4*)hp)[(b0 + b) * 128 + k4h];
            int k4 = 64 + k4h;
            xh[b * K4 + (k4 ^ (b & 7))] = v;
        }
        __syncthreads();

        // prefetch next step's x during compute
        if (t + 1 < TT) {
            xp1 = x4g[((long)(b0 + xb1) * TT + (t + 1)) * 64 + xk1];
            xp2 = x4g[((long)(b0 + xb2) * TT + (t + 1)) * 64 + xk1];
        }

        // ---- (b) GEMM: 4 gate-cols x 4 batches per thread, K-slice of 48 ----
        float4 acc[4][4];
        #pragma unroll
        for (int g = 0; g < 4; ++g)
            #pragma unroll
            for (int s = 0; s < 4; ++s)
                acc[g][s] = make_float4(0.f, 0.f, 0.f, 0.f);

        #pragma unroll
        for (int it = 0; it < 12; ++it) {
            const int k4 = ks * 12 + it;
            const int kw  = k4 ^ ct;
            const int kh0 = k4 ^ bt;
            const int kh1 = k4 ^ (bt + 4);
            float4 w0v = wl0[kw], w1v = wl1[kw], w2v = wl2[kw], w3v = wl3[kw];
            float4 h0v = xr0[kh0], h1v = xr1[kh1], h2v = xr2[kh0], h3v = xr3[kh1];
            FMA4(acc[0][0], w0v, h0v); FMA4(acc[0][1], w0v, h1v);
            FMA4(acc[0][2], w0v, h2v); FMA4(acc[0][3], w0v, h3v);
            FMA4(acc[1][0], w1v, h0v); FMA4(acc[1][1], w1v, h1v);
            FMA4(acc[1][2], w1v, h2v); FMA4(acc[1][3], w1v, h3v);
            FMA4(acc[2][0], w2v, h0v); FMA4(acc[2][1], w2v, h1v);
            FMA4(acc[2][2], w2v, h2v); FMA4(acc[2][3], w2v, h3v);
            FMA4(acc[3][0], w3v, h0v); FMA4(acc[3][1], w3v, h1v);
            FMA4(acc[3][2], w3v, h2v); FMA4(acc[3][3], w3v, h3v);
        }
        #pragma unroll
        for (int g = 0; g < 4; ++g) {
            #pragma unroll
            for (int s = 0; s < 4; ++s) {
                float4 a = acc[g][s];
                float z = (a.x + a.y) + (a.z + a.w);
                atomicAdd(&zsum[p][(g * 8 + ct) * 16 + (bt + 4 * s)], z);
            }
        }
        __syncthreads();

        // ---- (c) re-init other parity buffer + gate combine ----
        zsum[1 - p][tid] = biasreg;
        if (tid < 128) {
            const int b = tid >> 3, jj = tid & 7;
            float zi = zsum[p][(jj) * 16 + b];
            float zf = zsum[p][(8 + jj) * 16 + b];
            float zg = zsum[p][(16 + jj) * 16 + b];
            float zo = zsum[p][(24 + jj) * 16 + b];
            float iv = tanhf(zi);
            float fv = tanhf(zf);
            float gv = tanhf(zg);
            float ov = tanhf(zo);
            float c2 = fv * creg + iv * gv;
            float h2 = ov * tanhf(c2);
            creg = c2;
            hn[(b0 + b) * HH + (j0 + jj)] = h2;
            out[CTXF + ((long)((b0 + b) * TT + t)) * KX + DD + (j0 + jj)] = h2;
            if (t == TT - 1) out[(long)(b0 + b) * KX + DD + (j0 + jj)] = h2;
        }
        grid.sync();
    }
}

// ---------------------------------------------------------------------------
extern "C" void kernel_launch(void* const* d_in, const int* in_sizes, int n_in,
                              void* d_out, int out_size, void* d_ws, size_t ws_size,
                              hipStream_t stream) {
    (void)in_sizes; (void)n_in; (void)out_size; (void)ws_size;
    const float* x    = (const float*)d_in[0];
    const float* Wm   = (const float*)d_in[1];
    const float* Um   = (const float*)d_in[2];
    const float* bias = (const float*)d_in[3];
    float* out = (float*)d_out;
    float* ws  = (float*)d_ws;

    float* vut = ws;                   // 2048*768 floats
    float* h   = ws + 1572864;         // 2 * 64*512 floats (double buffer)

    hipLaunchKernelGGL(pack_vut, dim3(64, 24), dim3(256), 0, stream, Wm, Um, vut);
    hipLaunchKernelGGL(init_state, dim3(256), dim3(256), 0, stream, h);
    hipLaunchKernelGGL(xcopy, dim3(8209), dim3(256), 0, stream, x, out);

    void* args[] = {(void*)&vut, (void*)&bias, (void*)&x, (void*)&h, (void*)&out};
    hipLaunchCooperativeKernel((const void*)lstm_persist, dim3(256), dim3(512),
                               args, 0, stream);
}